// Round 9
// baseline (549.302 us; speedup 1.0000x reference)
//
#include <hip/hip_runtime.h>
#include <hip/hip_cooperative_groups.h>

namespace cg = cooperative_groups;

#define NTOK 8192
#define DDIM 1024
#define HDIM 2048
#define ODIM 1024
#define NEXP 8
#define OUTW (ODIM + NEXP)   // 1032
#define MT_MAX 64            // worst-case 128-row m-tiles per expert
#define WT_BLKS 8192         // wtrans tiles: W1 32x16x8 + W2 16x32x8
#define GA_BLKS (NTOK / 4)   // 2048 gather units (4 tokens each)
#define G1_TILES (NEXP * MT_MAX * (HDIM / 128))  // 8192
#define G2_TILES (NEXP * MT_MAX * (ODIM / 128))  // 4096

typedef __bf16 bf16_t;
typedef bf16_t bf16x8 __attribute__((ext_vector_type(8)));
typedef bf16_t bf16x4 __attribute__((ext_vector_type(4)));
typedef float f32x4 __attribute__((ext_vector_type(4)));

__device__ __forceinline__ void gld_lds16(bf16_t* lds, const bf16_t* g) {
  __builtin_amdgcn_global_load_lds(
      (__attribute__((address_space(1))) void*)g,
      (__attribute__((address_space(3))) void*)lds, 16, 0, 0);
}

// off[e] = 8-element prefix sum, recomputed per consumer from L2-hot cnt.
__device__ __forceinline__ void prefix_of(const int* __restrict__ cnt, int e,
                                          int& base, int& count) {
  base = 0; count = 0;
#pragma unroll
  for (int j = 0; j < NEXP; j++) {
    int c = cnt[j];
    if (j < e) base += c;
    if (j == e) count = c;
  }
}

// ---- shared phase bodies (all byte-identical to the proven round-7 kernels,
// parameterized on the unit index so they run standalone OR grid-strided) ----

__device__ __forceinline__ void route_unit(int u, int tid,
    const int* __restrict__ idx, float* __restrict__ out,
    int* __restrict__ rank, int* cnt, int* lcnt, int* lbase) {
  if (tid < NEXP) lcnt[tid] = 0;
  __syncthreads();
  int n = u * 256 + tid;
  int e = idx[n];
  int lr = atomicAdd(&lcnt[e], 1);
  __syncthreads();
  if (tid < NEXP) lbase[tid] = atomicAdd(&cnt[tid], lcnt[tid]);
  __syncthreads();
  rank[n] = lbase[e] + lr;
  float* o = out + (size_t)n * OUTW + ODIM;
#pragma unroll
  for (int j = 0; j < NEXP; j++) o[j] = (j == e) ? 1.0f : 0.0f;
}

// prep unit: u < WT_BLKS -> weight transpose 64x64 tile; else gather 4 tokens.
__device__ __forceinline__ void prep_unit(int u, int tid, float (*t)[65],
    const float* __restrict__ x, const int* __restrict__ idx,
    const int* __restrict__ rank, const int* __restrict__ cnt,
    bf16_t* __restrict__ xg, int* __restrict__ tok_of_pos,
    const float* __restrict__ s1, bf16_t* __restrict__ d1,
    const float* __restrict__ s2, bf16_t* __restrict__ d2) {
  if (u >= WT_BLKS) {  // ---- gather: tokens g*4 .. g*4+3 ----
    int g = u - WT_BLKS;
    float4 v[4];
    int pos[4];
#pragma unroll
    for (int ti = 0; ti < 4; ti++) {
      int n = g * 4 + ti;
      v[ti] = ((const float4*)(x + (size_t)n * DDIM))[tid];
      int e = idx[n];
      int base, cc;
      prefix_of(cnt, e, base, cc);
      pos[ti] = base + rank[n];
      if (tid == 0) tok_of_pos[pos[ti]] = n;
    }
#pragma unroll
    for (int ti = 0; ti < 4; ti++) {
      bf16x4 o;
      o[0] = (bf16_t)v[ti].x; o[1] = (bf16_t)v[ti].y;
      o[2] = (bf16_t)v[ti].z; o[3] = (bf16_t)v[ti].w;
      *(bf16x4*)(xg + (size_t)pos[ti] * DDIM + tid * 4) = o;
    }
    return;
  }
  // ---- wtrans: src [E][R][C] f32 -> dst [E][C][R] bf16, 64x64 tile ----
  // 256B-segment reads, 128B-segment writes; LDS stride 65 -> <=2-way (free).
  const float* src; bf16_t* dst; int R, C, bx, by, e;
  if (u < 4096) {        // W1: C=2048 (32 x-tiles), R=1024 (16 y-tiles)
    src = s1; dst = d1; R = DDIM; C = HDIM;
    bx = u & 31; by = (u >> 5) & 15; e = u >> 9;
  } else {               // W2: C=1024 (16 x-tiles), R=2048 (32 y-tiles)
    int b2 = u - 4096;
    src = s2; dst = d2; R = HDIM; C = ODIM;
    bx = b2 & 15; by = (b2 >> 4) & 31; e = b2 >> 9;
  }
  int c0 = bx * 64, r0g = by * 64;
  const float* s = src + (size_t)e * R * C;
#pragma unroll
  for (int p = 0; p < 4; p++) {
    int r = (tid >> 4) + p * 16;
    int c4 = (tid & 15) * 4;
    float4 v = *(const float4*)&s[(size_t)(r0g + r) * C + c0 + c4];
    t[r][c4 + 0] = v.x;
    t[r][c4 + 1] = v.y;
    t[r][c4 + 2] = v.z;
    t[r][c4 + 3] = v.w;
  }
  __syncthreads();
  bf16_t* d = dst + (size_t)e * R * C;
  int w = tid >> 6, l = tid & 63;
#pragma unroll
  for (int itc = 0; itc < 2; itc++) {
    int c = (l >> 3) + 8 * w + 32 * itc;
    int r0 = (l & 7) * 8;
    bf16x8 o;
#pragma unroll
    for (int j = 0; j < 8; j++) o[j] = (bf16_t)t[r0 + j][c];
    *(bf16x8*)&d[(size_t)(c0 + c) * R + r0g + r0] = o;
  }
}

// FROZEN round-4 GEMM tile body (62.7us proven): 128x128, BK=32, single
// 16KB-per-matrix buffer, stage -> barrier -> 16 MFMA -> barrier. All
// pipelining/tile variants (2-phase dbuf, 8-phase vmcnt, BK=64, 256x128)
// measured or derived slower. XOR swizzle: row r slot qs holds global
// k-quarter qs^(r&3); fragment reads slot q^(mrow&3) -> conflict-free.
template <int KDIM, int NCOLS, int MTG, bool TO_BF16>
__device__ __forceinline__ void gemm_tile(int b, bf16_t* lA, bf16_t* lB,
    const bf16_t* __restrict__ A, const bf16_t* __restrict__ Bt,
    const float* __restrict__ bias, const int* __restrict__ cnt,
    const int* __restrict__ tok_of_pos,
    bf16_t* __restrict__ outb, float* __restrict__ outf) {
  constexpr int NT = NCOLS / 128;
  const int e = b & 7;           // expert pinned to one XCD
  int t = b >> 3;
  const int mtl = t % MTG;
  t /= MTG;
  const int nt = t % NT;
  const int g = t / NT;
  const int mt = g * MTG + mtl;

  int base, count;
  prefix_of(cnt, e, base, count);
  if (mt * 128 >= count) return;

  const int tid = threadIdx.x;
  const int lane = tid & 63;
  const int wave = tid >> 6;
  const int mrow = lane & 15;
  const int q = lane >> 4;
  const int wm = (wave & 1) * 64;
  const int wn = (wave >> 1) * 64;

  const bf16_t* pA[2];
  const bf16_t* pB[2];
#pragma unroll
  for (int s = 0; s < 2; s++) {
    int lrow = wave * 32 + s * 16 + (lane >> 2);
    int kq = (lane & 3) ^ (lrow & 3);
    int gr = base + mt * 128 + lrow;
    if (gr > NTOK - 1) gr = NTOK - 1;  // clamp: garbage rows masked at store
    pA[s] = A + (size_t)gr * KDIM + kq * 8;
    int nrow = nt * 128 + lrow;
    pB[s] = Bt + ((size_t)e * NCOLS + nrow) * KDIM + kq * 8;
  }

  f32x4 acc[4][4] = {};
  const bf16_t* la0 = &lA[(wm + mrow) * 32 + ((q ^ (mrow & 3)) * 8)];
  const bf16_t* lb0 = &lB[(wn + mrow) * 32 + ((q ^ (mrow & 3)) * 8)];

  for (int kk = 0; kk < KDIM; kk += 32) {
#pragma unroll
    for (int s = 0; s < 2; s++) {
      gld_lds16(&lA[(wave * 2 + s) * 512], pA[s] + kk);
      gld_lds16(&lB[(wave * 2 + s) * 512], pB[s] + kk);
    }
    __syncthreads();
    bf16x8 af[4], bfr[4];
#pragma unroll
    for (int i = 0; i < 4; i++) {
      af[i]  = *(const bf16x8*)(la0 + i * 16 * 32);
      bfr[i] = *(const bf16x8*)(lb0 + i * 16 * 32);
    }
#pragma unroll
    for (int i = 0; i < 4; i++)
#pragma unroll
      for (int j = 0; j < 4; j++)
        acc[i][j] = __builtin_amdgcn_mfma_f32_16x16x32_bf16(af[i], bfr[j], acc[i][j], 0, 0, 0);
    __syncthreads();
  }

  const int mlimit = count - mt * 128;
  float bs[4];
#pragma unroll
  for (int j = 0; j < 4; j++)
    bs[j] = bias[(size_t)e * NCOLS + nt * 128 + wn + j * 16 + mrow];

#pragma unroll
  for (int i = 0; i < 4; i++) {
#pragma unroll
    for (int r = 0; r < 4; r++) {
      int ml = wm + i * 16 + q * 4 + r;
      if (ml < mlimit) {
        int prow = base + mt * 128 + ml;
        if constexpr (TO_BF16) {
          bf16_t* orow = outb + (size_t)prow * NCOLS;
#pragma unroll
          for (int j = 0; j < 4; j++)
            orow[nt * 128 + wn + j * 16 + mrow] = (bf16_t)(acc[i][j][r] + bs[j]);
        } else {
          int tok = tok_of_pos[prow];
          float* orow = outf + (size_t)tok * OUTW;
#pragma unroll
          for (int j = 0; j < 4; j++)
            orow[nt * 128 + wn + j * 16 + mrow] = acc[i][j][r] + bs[j];
        }
      }
    }
  }
}

// =================== persistent cooperative mega-kernel ====================
// route -> grid.sync -> prep -> grid.sync -> GEMM1 -> grid.sync -> GEMM2.
// Eliminates the 4 inter-dispatch gaps (~96us of measured dark time: wall
// 304.8 vs kernel-sum ~208). Every phase body is the proven round-7 code in
// a grid-stride loop. Shared mem 33.1KB x 4 blocks/CU = 132KB <= 160KB;
// __launch_bounds__(256,4) pins VGPR<=128 so 4 blocks/CU holds; grid is
// clamped by the occupancy query so cooperative co-residency is guaranteed.
__global__ __launch_bounds__(256, 4) void mega_kernel(
    const float* __restrict__ x, const float* __restrict__ W1,
    const float* __restrict__ b1, const float* __restrict__ W2,
    const float* __restrict__ b2, const int* __restrict__ idx,
    float* __restrict__ out, bf16_t* __restrict__ xg, bf16_t* __restrict__ hg,
    bf16_t* __restrict__ Wt1, bf16_t* __restrict__ Wt2,
    int* __restrict__ tok, int* __restrict__ rank, int* __restrict__ cnt) {
  cg::grid_group grid = cg::this_grid();
  __shared__ float t[64][65];
  __shared__ int lcnt[NEXP];
  __shared__ int lbase[NEXP];
  __shared__ bf16_t lA[128 * 32];
  __shared__ bf16_t lB[128 * 32];
  const int tid = threadIdx.x;
  const int nb = gridDim.x;

  // phase 0: route (32 units)
  for (int u = blockIdx.x; u < NTOK / 256; u += nb)
    route_unit(u, tid, idx, out, rank, cnt, lcnt, lbase);
  grid.sync();
  // phase 1: prep (8192 wtrans + 2048 gather units)
  for (int u = blockIdx.x; u < WT_BLKS + GA_BLKS; u += nb) {
    prep_unit(u, tid, t, x, idx, rank, cnt, xg, tok, W1, Wt1, W2, Wt2);
    __syncthreads();  // WAR on t[][] between consecutive wtrans units
  }
  grid.sync();
  // phase 2: GEMM1  K=1024 N=2048 MTG=8 (e = tile&7 == blockIdx&7: XCD-pinned)
  for (int b = blockIdx.x; b < G1_TILES; b += nb)
    gemm_tile<DDIM, HDIM, 8, true>(b, lA, lB, xg, Wt1, b1, cnt, tok, hg, nullptr);
  grid.sync();
  // phase 3: GEMM2  K=2048 N=1024 MTG=4
  for (int b = blockIdx.x; b < G2_TILES; b += nb)
    gemm_tile<HDIM, ODIM, 4, false>(b, lA, lB, hg, Wt2, b2, cnt, tok, nullptr, out);
}

// ====================== proven 5-dispatch fallback =========================
__global__ void route_kernel(const int* __restrict__ idx, float* __restrict__ out,
                             int* __restrict__ rank, int* cnt) {
  __shared__ int lcnt[NEXP];
  __shared__ int lbase[NEXP];
  route_unit(blockIdx.x, threadIdx.x, idx, out, rank, cnt, lcnt, lbase);
}

__global__ __launch_bounds__(256) void prep_kernel(
    const float* __restrict__ x, const int* __restrict__ idx,
    const int* __restrict__ rank, const int* __restrict__ cnt,
    bf16_t* __restrict__ xg, int* __restrict__ tok_of_pos,
    const float* __restrict__ s1, bf16_t* __restrict__ d1,
    const float* __restrict__ s2, bf16_t* __restrict__ d2) {
  __shared__ float t[64][65];
  prep_unit(blockIdx.x, threadIdx.x, t, x, idx, rank, cnt, xg, tok_of_pos,
            s1, d1, s2, d2);
}

template <int KDIM, int NCOLS, int MTG, bool TO_BF16>
__global__ __launch_bounds__(256) void gemm_kernel(
    const bf16_t* __restrict__ A, const bf16_t* __restrict__ Bt,
    const float* __restrict__ bias, const int* __restrict__ cnt,
    const int* __restrict__ tok_of_pos,
    bf16_t* __restrict__ outb, float* __restrict__ outf) {
  __shared__ bf16_t lA[128 * 32];
  __shared__ bf16_t lB[128 * 32];
  gemm_tile<KDIM, NCOLS, MTG, TO_BF16>(blockIdx.x, lA, lB, A, Bt, bias, cnt,
                                       tok_of_pos, outb, outf);
}

extern "C" void kernel_launch(void* const* d_in, const int* in_sizes, int n_in,
                              void* d_out, int out_size, void* d_ws, size_t ws_size,
                              hipStream_t stream) {
  const float* x  = (const float*)d_in[0];
  const float* W1 = (const float*)d_in[1];
  const float* b1 = (const float*)d_in[2];
  const float* W2 = (const float*)d_in[3];
  const float* b2 = (const float*)d_in[4];
  const int* idx  = (const int*)d_in[5];
  float* out = (float*)d_out;

  char* ws = (char*)d_ws;
  bf16_t* xg  = (bf16_t*)(ws);                 // 16 MB  [N][D] bf16
  bf16_t* hg  = (bf16_t*)(ws + 16777216);      // 32 MB  [N][H] bf16
  bf16_t* Wt1 = (bf16_t*)(ws + 50331648);      // 32 MB  [E][H][D] bf16
  bf16_t* Wt2 = (bf16_t*)(ws + 83886080);      // 32 MB  [E][O][H] bf16
  int* tok    = (int*)(ws + 117440512);        // 32 KB
  int* rank   = (int*)(ws + 117473280);        // 32 KB
  int* cnt    = (int*)(ws + 117506048);        // 32 B  (proven layout)

  hipMemsetAsync(cnt, 0, NEXP * sizeof(int), stream);

  int maxb = 0;
  hipError_t qe = hipOccupancyMaxActiveBlocksPerMultiprocessor(&maxb, mega_kernel, 256, 0);
  if (qe == hipSuccess && maxb >= 1) {
    int nb = maxb * 256;           // 256 CUs; multiple of 8 keeps XCD pinning
    if (nb > 1024) nb = 1024;
    void* args[] = {(void*)&x, (void*)&W1, (void*)&b1, (void*)&W2, (void*)&b2,
                    (void*)&idx, (void*)&out, (void*)&xg, (void*)&hg,
                    (void*)&Wt1, (void*)&Wt2, (void*)&tok, (void*)&rank,
                    (void*)&cnt};
    hipError_t le = hipLaunchCooperativeKernel(mega_kernel, dim3(nb), dim3(256),
                                               args, 0, stream);
    if (le == hipSuccess) return;
    (void)hipGetLastError();  // clear error state, fall through to fallback
  }

  // fallback: proven round-7 5-dispatch path (304.8us)
  route_kernel<<<NTOK / 256, 256, 0, stream>>>(idx, out, rank, cnt);
  prep_kernel<<<WT_BLKS + GA_BLKS, 256, 0, stream>>>(x, idx, rank, cnt, xg, tok,
                                                     W1, Wt1, W2, Wt2);
  gemm_kernel<DDIM, HDIM, 8, true><<<G1_TILES, 256, 0, stream>>>(
      xg, Wt1, b1, cnt, tok, hg, nullptr);
  gemm_kernel<HDIM, ODIM, 4, false><<<G2_TILES, 256, 0, stream>>>(
      hg, Wt2, b2, cnt, tok, nullptr, out);
}